// Round 9
// baseline (245.335 us; speedup 1.0000x reference)
//
#include <hip/hip_runtime.h>
#include <math.h>

#define S_LEN 4096
#define F_DIM 512
#define PSPLIT 8
#define FIXED_M 4.0f

typedef __attribute__((ext_vector_type(8))) short bf16x8;
typedef __attribute__((ext_vector_type(4))) float f32x4;

__device__ __forceinline__ unsigned short f2bf(float x) {
    union { float f; unsigned u; } v; v.f = x;
    unsigned r = v.u + 0x7fffu + ((v.u >> 16) & 1u);
    return (unsigned short)(r >> 16);
}
__device__ __forceinline__ float bf2f(unsigned short b) {
    union { unsigned u; float f; } v; v.u = ((unsigned)b) << 16;
    return v.f;
}
__device__ __forceinline__ void load_lds16(const void* g, void* l) {
    __builtin_amdgcn_global_load_lds(
        (const __attribute__((address_space(1))) unsigned int*)g,
        (__attribute__((address_space(3))) unsigned int*)l, 16, 0, 0);
}

// ---------------- fused fp32 -> bf16 casts ----------------
struct CastArgs {
    const float* src[7];
    unsigned short* dst[7];
    int n4[7];
};
__global__ void cast_all(CastArgs a) {
    int r = blockIdx.y;
    int i = blockIdx.x * blockDim.x + threadIdx.x;
    if (i >= a.n4[r]) return;
    float4 v = ((const float4*)a.src[r])[i];
    ushort4 o;
    o.x = f2bf(v.x); o.y = f2bf(v.y); o.z = f2bf(v.z); o.w = f2bf(v.w);
    ((ushort4*)a.dst[r])[i] = o;
}

// ---------------- bf16 transpose: src [S][F] -> dst [F][S] ----------------
__global__ void transpose_bf16(const unsigned short* __restrict__ src,
                               unsigned short* __restrict__ dst) {
    __shared__ __align__(16) unsigned short tile[64][72];
    const int s0 = blockIdx.x * 64, f0 = blockIdx.y * 64;
    const int tid = threadIdx.x;
#pragma unroll
    for (int it = 0; it < 2; ++it) {
        int u = it * 256 + tid;
        int r = u >> 3, c = (u & 7) * 8;
        *(uint4*)&tile[r][c] = *(const uint4*)(src + (size_t)(s0 + r) * F_DIM + f0 + c);
    }
    __syncthreads();
#pragma unroll
    for (int it = 0; it < 2; ++it) {
        int u = it * 256 + tid;
        int fl = u >> 3, sc = (u & 7) * 8;
        unsigned short tmp[8];
#pragma unroll
        for (int i = 0; i < 8; ++i) tmp[i] = tile[sc + i][fl];
        *(uint4*)(dst + (size_t)(f0 + fl) * S_LEN + s0 + sc) = *(uint4*)tmp;
    }
}

// ======== shared K-loop macro: BK=64, frag-packed LDS, 8 iters for K=512 ========
// As/Bs hold 16 frags of 512 shorts each (frag = 16 rows x 32 k).
#define GEMM_KLOOP(XPTR, LDX, WPTR, LDW, KBEG, KEND)                                  \
    for (int k0 = (KBEG); k0 < (KEND); k0 += 64) {                                    \
        __syncthreads();                                                              \
        _Pragma("unroll")                                                             \
        for (int i = 0; i < 2; ++i) {                                                 \
            int c = w * 2 + i;                                                        \
            _Pragma("unroll")                                                         \
            for (int kh = 0; kh < 2; ++kh) {                                          \
                load_lds16((XPTR) + (size_t)(m0 + c * 16 + ln) * (LDX) + k0 + kh * 32 + quad * 8, \
                           &As[(c * 2 + kh) * 512]);                                  \
                load_lds16((WPTR) + (size_t)(n0 + c * 16 + ln) * (LDW) + k0 + kh * 32 + quad * 8, \
                           &Bs[(c * 2 + kh) * 512]);                                  \
            }                                                                         \
        }                                                                             \
        __syncthreads();                                                              \
        _Pragma("unroll")                                                             \
        for (int kh = 0; kh < 2; ++kh) {                                              \
            bf16x8 af[4], bfr[4];                                                     \
            _Pragma("unroll")                                                         \
            for (int mt = 0; mt < 4; ++mt)                                            \
                af[mt] = *(const bf16x8*)&As[((wr * 4 + mt) * 2 + kh) * 512 + l * 8];  \
            _Pragma("unroll")                                                         \
            for (int nt = 0; nt < 4; ++nt)                                            \
                bfr[nt] = *(const bf16x8*)&Bs[((wc * 4 + nt) * 2 + kh) * 512 + l * 8]; \
            _Pragma("unroll")                                                         \
            for (int mt = 0; mt < 4; ++mt)                                            \
                _Pragma("unroll")                                                     \
                for (int nt = 0; nt < 4; ++nt)                                        \
                    acc[mt][nt] = __builtin_amdgcn_mfma_f32_16x16x32_bf16(            \
                        af[mt], bfr[nt], acc[mt][nt], 0, 0, 0);                       \
        }                                                                             \
    }

// ---------------- 128x128 GEMM: out = op(X @ W^T + b) ----------------
struct GemmDesc {
    const unsigned short* X;
    const unsigned short* W;
    const float* bias;
    unsigned short* out_bf;
    float* out_f32;
    int relu;
};
struct GemmArgs { GemmDesc d[5]; };

__launch_bounds__(256, 2)
__global__ void gemm128(GemmArgs args) {
    __shared__ __align__(16) unsigned short As[16 * 512];
    __shared__ __align__(16) unsigned short Bs[16 * 512];
    const GemmDesc d = args.d[blockIdx.y >> 2];
    const int n0 = (blockIdx.y & 3) * 128;
    const int m0 = blockIdx.x * 128;
    const int tid = threadIdx.x;
    const int w = tid >> 6, l = tid & 63, quad = l >> 4, ln = l & 15;
    const int wr = w >> 1, wc = w & 1;

    f32x4 acc[4][4];
    f32x4 zero4 = {0.f, 0.f, 0.f, 0.f};
#pragma unroll
    for (int i = 0; i < 4; ++i)
#pragma unroll
        for (int j = 0; j < 4; ++j) acc[i][j] = zero4;

    GEMM_KLOOP(d.X, F_DIM, d.W, F_DIM, 0, F_DIM)

#pragma unroll
    for (int mt = 0; mt < 4; ++mt)
#pragma unroll
        for (int nt = 0; nt < 4; ++nt)
#pragma unroll
            for (int r = 0; r < 4; ++r) {
                int row = m0 + wr * 64 + mt * 16 + quad * 4 + r;
                int col = n0 + wc * 64 + nt * 16 + ln;
                float vv = acc[mt][nt][r] + d.bias[col];
                if (d.relu) vv = fmaxf(vv, 0.f);
                if (d.out_bf)  d.out_bf[(size_t)row * F_DIM + col] = f2bf(vv);
                if (d.out_f32) d.out_f32[(size_t)row * F_DIM + col] = vv;
            }
}

// ---------------- gemm_exp: P = exp(scale*(qq @ kk^T) - M) + per-block row sums ----------------
__launch_bounds__(256, 2)
__global__ void gemm_exp(const unsigned short* __restrict__ X,   // qq [S][F]
                         const unsigned short* __restrict__ W,   // kk [S][F]
                         unsigned short* __restrict__ P,         // [S][S]
                         float* __restrict__ lpart) {            // [32][S]
    __shared__ __align__(16) unsigned short As[16 * 512];
    __shared__ __align__(16) unsigned short Bs[16 * 512];
    __shared__ float lsum[2][2][64];
    const float scale = 0.04415108f;  // 1/sqrt(513)
    const int nb = blockIdx.y;
    const int n0 = nb * 128;
    const int m0 = blockIdx.x * 128;
    const int tid = threadIdx.x;
    const int w = tid >> 6, l = tid & 63, quad = l >> 4, ln = l & 15;
    const int wr = w >> 1, wc = w & 1;

    f32x4 acc[4][4];
    f32x4 zero4 = {0.f, 0.f, 0.f, 0.f};
#pragma unroll
    for (int i = 0; i < 4; ++i)
#pragma unroll
        for (int j = 0; j < 4; ++j) acc[i][j] = zero4;

    GEMM_KLOOP(X, F_DIM, W, F_DIM, 0, F_DIM)

    float rs[4][4];
#pragma unroll
    for (int mt = 0; mt < 4; ++mt)
#pragma unroll
        for (int r = 0; r < 4; ++r) rs[mt][r] = 0.f;

#pragma unroll
    for (int mt = 0; mt < 4; ++mt)
#pragma unroll
        for (int nt = 0; nt < 4; ++nt)
#pragma unroll
            for (int r = 0; r < 4; ++r) {
                int row = m0 + wr * 64 + mt * 16 + quad * 4 + r;
                int col = n0 + wc * 64 + nt * 16 + ln;
                float p = __expf(acc[mt][nt][r] * scale - FIXED_M);
                P[(size_t)row * S_LEN + col] = f2bf(p);
                rs[mt][r] += p;
            }
#pragma unroll
    for (int mt = 0; mt < 4; ++mt)
#pragma unroll
        for (int r = 0; r < 4; ++r) {
            float v = rs[mt][r];
            v += __shfl_xor(v, 1);
            v += __shfl_xor(v, 2);
            v += __shfl_xor(v, 4);
            v += __shfl_xor(v, 8);
            if (ln == 0) lsum[wr][wc][mt * 16 + quad * 4 + r] = v;
        }
    __syncthreads();
    if (tid < 128)
        lpart[(size_t)nb * S_LEN + m0 + tid] =
            lsum[tid >> 6][0][tid & 63] + lsum[tid >> 6][1][tid & 63];
}

// ---------------- gemm_pv: O_p[split] = P[:, ks] @ vt[:, ks]^T (bf16 partials) ----------------
// grid (32, 32): nb = y&3 (n0 over F), split = y>>2 (koff = split*512).
__launch_bounds__(256, 2)
__global__ void gemm_pv(const unsigned short* __restrict__ P,   // [S][S]
                        const unsigned short* __restrict__ vt,  // [F][S]
                        unsigned short* __restrict__ O_p) {     // [PSPLIT][S][F] bf16
    __shared__ __align__(16) unsigned short As[16 * 512];
    __shared__ __align__(16) unsigned short Bs[16 * 512];
    const int nb = blockIdx.y & 3;
    const int split = blockIdx.y >> 2;
    const int n0 = nb * 128;
    const int m0 = blockIdx.x * 128;
    const int koff = split * (S_LEN / PSPLIT);
    const int tid = threadIdx.x;
    const int w = tid >> 6, l = tid & 63, quad = l >> 4, ln = l & 15;
    const int wr = w >> 1, wc = w & 1;

    f32x4 acc[4][4];
    f32x4 zero4 = {0.f, 0.f, 0.f, 0.f};
#pragma unroll
    for (int i = 0; i < 4; ++i)
#pragma unroll
        for (int j = 0; j < 4; ++j) acc[i][j] = zero4;

    GEMM_KLOOP(P, S_LEN, vt, S_LEN, koff, koff + S_LEN / PSPLIT)

    unsigned short* Op = O_p + (size_t)split * S_LEN * F_DIM;
#pragma unroll
    for (int mt = 0; mt < 4; ++mt)
#pragma unroll
        for (int nt = 0; nt < 4; ++nt)
#pragma unroll
            for (int r = 0; r < 4; ++r) {
                int row = m0 + wr * 64 + mt * 16 + quad * 4 + r;
                int col = n0 + wc * 64 + nt * 16 + ln;
                Op[(size_t)row * F_DIM + col] = f2bf(acc[mt][nt][r]);
            }
}

// ---------------- combine: denom + q_att dot + split-sum + elementwise fusion ----------------
__global__ void combine_kernel(const unsigned short* __restrict__ O_p,
                               const float* __restrict__ lpart,
                               const unsigned short* __restrict__ qq,
                               const unsigned short* __restrict__ qk,
                               const unsigned short* __restrict__ qv,
                               unsigned short* __restrict__ res_bf) {
    const float scale = 0.04415108f;
    int row = blockIdx.x;
    int t = threadIdx.x;  // 128 threads = 2 waves
    int wv = t >> 6, l = t & 63;
    __shared__ float wsum[2];

    ushort4 a = *(const ushort4*)(qq + (size_t)row * F_DIM + t * 4);
    ushort4 b = *(const ushort4*)(qk + (size_t)row * F_DIM + t * 4);
    float part = bf2f(a.x) * bf2f(b.x) + bf2f(a.y) * bf2f(b.y) +
                 bf2f(a.z) * bf2f(b.z) + bf2f(a.w) * bf2f(b.w);
#pragma unroll
    for (int off = 32; off >= 1; off >>= 1) part += __shfl_xor(part, off);
    if (l == 0) wsum[wv] = part;
    __syncthreads();
    float qa = wsum[0] + wsum[1];

    float denom = __expf(qa * scale - FIXED_M);  // extra column: denominator only
#pragma unroll
    for (int i = 0; i < 32; ++i) denom += lpart[(size_t)i * S_LEN + row];
    float inv = 1.f / denom;

    for (int f = t; f < F_DIM; f += 128) {
        float acc = 0.f;
#pragma unroll
        for (int i = 0; i < PSPLIT; ++i)
            acc += bf2f(O_p[((size_t)i * S_LEN + row) * F_DIM + f]);
        float r = bf2f(qv[(size_t)row * F_DIM + f]) * qa + acc * inv;
        res_bf[(size_t)row * F_DIM + f] = f2bf(r);
    }
}

extern "C" void kernel_launch(void* const* d_in, const int* in_sizes, int n_in,
                              void* d_out, int out_size, void* d_ws, size_t ws_size,
                              hipStream_t stream) {
    const float* q  = (const float*)d_in[0];
    const float* k  = (const float*)d_in[1];
    const float* v  = (const float*)d_in[2];
    const float* Wq = (const float*)d_in[3];
    const float* bq = (const float*)d_in[4];
    const float* Wk = (const float*)d_in[5];
    const float* bk = (const float*)d_in[6];
    const float* Wv = (const float*)d_in[7];
    const float* bv = (const float*)d_in[8];
    const float* Wo = (const float*)d_in[9];
    const float* bo = (const float*)d_in[10];
    float* out = (float*)d_out;

    char* p = (char*)d_ws;
    auto alloc = [&](size_t bytes) -> char* {
        char* r = p; p += (bytes + 255) & ~(size_t)255; return r;
    };
    const size_t SF = (size_t)S_LEN * F_DIM;
    unsigned short* q_bf  = (unsigned short*)alloc(SF * 2);
    unsigned short* k_bf  = (unsigned short*)alloc(SF * 2);
    unsigned short* v_bf  = (unsigned short*)alloc(SF * 2);
    unsigned short* qq_bf = (unsigned short*)alloc(SF * 2);
    unsigned short* kk_bf = (unsigned short*)alloc(SF * 2);
    unsigned short* vv_bf = (unsigned short*)alloc(SF * 2);
    unsigned short* vt_bf = (unsigned short*)alloc(SF * 2);
    unsigned short* qk_bf = (unsigned short*)alloc(SF * 2);
    unsigned short* qv_bf = (unsigned short*)alloc(SF * 2);
    unsigned short* res_bf = (unsigned short*)alloc(SF * 2);
    unsigned short* wq_bf = (unsigned short*)alloc((size_t)F_DIM * F_DIM * 2);
    unsigned short* wk_bf = (unsigned short*)alloc((size_t)F_DIM * F_DIM * 2);
    unsigned short* wv_bf = (unsigned short*)alloc((size_t)F_DIM * F_DIM * 2);
    unsigned short* wo_bf = (unsigned short*)alloc((size_t)F_DIM * F_DIM * 2);
    unsigned short* P_bf  = (unsigned short*)alloc((size_t)S_LEN * S_LEN * 2);  // 33.5 MB
    float* lpart = (float*)alloc((size_t)32 * S_LEN * 4);
    unsigned short* O_p = (unsigned short*)alloc((size_t)PSPLIT * SF * 2);      // 32 MB

    CastArgs ca;
    ca.src[0] = q;  ca.dst[0] = q_bf;  ca.n4[0] = (int)(SF / 4);
    ca.src[1] = k;  ca.dst[1] = k_bf;  ca.n4[1] = (int)(SF / 4);
    ca.src[2] = v;  ca.dst[2] = v_bf;  ca.n4[2] = (int)(SF / 4);
    ca.src[3] = Wq; ca.dst[3] = wq_bf; ca.n4[3] = F_DIM * F_DIM / 4;
    ca.src[4] = Wk; ca.dst[4] = wk_bf; ca.n4[4] = F_DIM * F_DIM / 4;
    ca.src[5] = Wv; ca.dst[5] = wv_bf; ca.n4[5] = F_DIM * F_DIM / 4;
    ca.src[6] = Wo; ca.dst[6] = wo_bf; ca.n4[6] = F_DIM * F_DIM / 4;
    cast_all<<<dim3((unsigned)(SF / 4 / 256), 7), 256, 0, stream>>>(ca);

    GemmArgs ga;
    ga.d[0] = { q_bf, wq_bf, bq, qq_bf, nullptr, 1 };
    ga.d[1] = { k_bf, wk_bf, bk, kk_bf, nullptr, 1 };
    ga.d[2] = { v_bf, wv_bf, bv, vv_bf, nullptr, 1 };
    ga.d[3] = { q_bf, wk_bf, bk, qk_bf, nullptr, 0 };
    ga.d[4] = { q_bf, wv_bf, bv, qv_bf, nullptr, 0 };
    gemm128<<<dim3(S_LEN / 128, 20), 256, 0, stream>>>(ga);

    transpose_bf16<<<dim3(S_LEN / 64, F_DIM / 64), 256, 0, stream>>>(vv_bf, vt_bf);

    gemm_exp<<<dim3(S_LEN / 128, S_LEN / 128), 256, 0, stream>>>(qq_bf, kk_bf, P_bf, lpart);

    gemm_pv<<<dim3(S_LEN / 128, 4 * PSPLIT), 256, 0, stream>>>(P_bf, vt_bf, O_p);

    combine_kernel<<<S_LEN, 128, 0, stream>>>(O_p, lpart, qq_bf, qk_bf, qv_bf, res_bf);

    GemmArgs ga2{};
    ga2.d[0] = { res_bf, wo_bf, bo, nullptr, out, 1 };
    gemm128<<<dim3(S_LEN / 128, 4), 256, 0, stream>>>(ga2);
}

// Round 10
// 219.094 us; speedup vs baseline: 1.1198x; 1.1198x over previous
//
#include <hip/hip_runtime.h>
#include <math.h>

#define S_LEN 4096
#define F_DIM 512
#define PSPLIT 8
#define FIXED_M 4.0f

typedef __attribute__((ext_vector_type(8))) short bf16x8;
typedef __attribute__((ext_vector_type(4))) float f32x4;

__device__ __forceinline__ unsigned short f2bf(float x) {
    union { float f; unsigned u; } v; v.f = x;
    unsigned r = v.u + 0x7fffu + ((v.u >> 16) & 1u);
    return (unsigned short)(r >> 16);
}
__device__ __forceinline__ float bf2f(unsigned short b) {
    union { unsigned u; float f; } v; v.u = ((unsigned)b) << 16;
    return v.f;
}
__device__ __forceinline__ void load_lds16(const void* g, void* l) {
    __builtin_amdgcn_global_load_lds(
        (const __attribute__((address_space(1))) unsigned int*)g,
        (__attribute__((address_space(3))) unsigned int*)l, 16, 0, 0);
}

// ---------------- fused fp32 -> bf16 casts ----------------
struct CastArgs {
    const float* src[7];
    unsigned short* dst[7];
    int n4[7];
};
__global__ void cast_all(CastArgs a) {
    int r = blockIdx.y;
    int i = blockIdx.x * blockDim.x + threadIdx.x;
    if (i >= a.n4[r]) return;
    float4 v = ((const float4*)a.src[r])[i];
    ushort4 o;
    o.x = f2bf(v.x); o.y = f2bf(v.y); o.z = f2bf(v.z); o.w = f2bf(v.w);
    ((ushort4*)a.dst[r])[i] = o;
}

// ---------------- bf16 transpose: src [S][F] -> dst [F][S] ----------------
__global__ void transpose_bf16(const unsigned short* __restrict__ src,
                               unsigned short* __restrict__ dst) {
    __shared__ __align__(16) unsigned short tile[64][72];
    const int s0 = blockIdx.x * 64, f0 = blockIdx.y * 64;
    const int tid = threadIdx.x;
#pragma unroll
    for (int it = 0; it < 2; ++it) {
        int u = it * 256 + tid;
        int r = u >> 3, c = (u & 7) * 8;
        *(uint4*)&tile[r][c] = *(const uint4*)(src + (size_t)(s0 + r) * F_DIM + f0 + c);
    }
    __syncthreads();
#pragma unroll
    for (int it = 0; it < 2; ++it) {
        int u = it * 256 + tid;
        int fl = u >> 3, sc = (u & 7) * 8;
        unsigned short tmp[8];
#pragma unroll
        for (int i = 0; i < 8; ++i) tmp[i] = tile[sc + i][fl];
        *(uint4*)(dst + (size_t)(f0 + fl) * S_LEN + s0 + sc) = *(uint4*)tmp;
    }
}

// ======== 128x128 K-loop (BK=64) — used by projection / final gemms ========
#define GEMM_KLOOP(XPTR, LDX, WPTR, LDW, KBEG, KEND)                                  \
    for (int k0 = (KBEG); k0 < (KEND); k0 += 64) {                                    \
        __syncthreads();                                                              \
        _Pragma("unroll")                                                             \
        for (int i = 0; i < 2; ++i) {                                                 \
            int c = w * 2 + i;                                                        \
            _Pragma("unroll")                                                         \
            for (int kh = 0; kh < 2; ++kh) {                                          \
                load_lds16((XPTR) + (size_t)(m0 + c * 16 + ln) * (LDX) + k0 + kh * 32 + quad * 8, \
                           &As[(c * 2 + kh) * 512]);                                  \
                load_lds16((WPTR) + (size_t)(n0 + c * 16 + ln) * (LDW) + k0 + kh * 32 + quad * 8, \
                           &Bs[(c * 2 + kh) * 512]);                                  \
            }                                                                         \
        }                                                                             \
        __syncthreads();                                                              \
        _Pragma("unroll")                                                             \
        for (int kh = 0; kh < 2; ++kh) {                                              \
            bf16x8 af[4], bfr[4];                                                     \
            _Pragma("unroll")                                                         \
            for (int mt = 0; mt < 4; ++mt)                                            \
                af[mt] = *(const bf16x8*)&As[((wr * 4 + mt) * 2 + kh) * 512 + l * 8];  \
            _Pragma("unroll")                                                         \
            for (int nt = 0; nt < 4; ++nt)                                            \
                bfr[nt] = *(const bf16x8*)&Bs[((wc * 4 + nt) * 2 + kh) * 512 + l * 8]; \
            _Pragma("unroll")                                                         \
            for (int mt = 0; mt < 4; ++mt)                                            \
                _Pragma("unroll")                                                     \
                for (int nt = 0; nt < 4; ++nt)                                        \
                    acc[mt][nt] = __builtin_amdgcn_mfma_f32_16x16x32_bf16(            \
                        af[mt], bfr[nt], acc[mt][nt], 0, 0, 0);                       \
        }                                                                             \
    }

// ======== 256x128 K-loop (BK=64) — attention gemms ========
// As: 32 frags (row-group g=0..15, kh=0..1); Bs: 16 frags (col-group 0..7, kh).
// Wave w computes rows [m0+w*64, +64) x all 128 cols: acc[4][8].
#define KLOOP256(XPTR, LDX, WPTR, LDW, KBEG, KEND)                                    \
    for (int k0 = (KBEG); k0 < (KEND); k0 += 64) {                                    \
        __syncthreads();                                                              \
        _Pragma("unroll")                                                             \
        for (int i = 0; i < 4; ++i) {                                                 \
            int g = w * 4 + i;                                                        \
            _Pragma("unroll")                                                         \
            for (int kh = 0; kh < 2; ++kh)                                            \
                load_lds16((XPTR) + (size_t)(m0 + g * 16 + ln) * (LDX) + k0 + kh * 32 + quad * 8, \
                           &As[(g * 2 + kh) * 512]);                                  \
        }                                                                             \
        _Pragma("unroll")                                                             \
        for (int i = 0; i < 2; ++i) {                                                 \
            int g2 = w * 2 + i;                                                       \
            _Pragma("unroll")                                                         \
            for (int kh = 0; kh < 2; ++kh)                                            \
                load_lds16((WPTR) + (size_t)(n0 + g2 * 16 + ln) * (LDW) + k0 + kh * 32 + quad * 8, \
                           &Bs[(g2 * 2 + kh) * 512]);                                 \
        }                                                                             \
        __syncthreads();                                                              \
        _Pragma("unroll")                                                             \
        for (int kh = 0; kh < 2; ++kh) {                                              \
            bf16x8 af[4], bfr[8];                                                     \
            _Pragma("unroll")                                                         \
            for (int mt = 0; mt < 4; ++mt)                                            \
                af[mt] = *(const bf16x8*)&As[((w * 4 + mt) * 2 + kh) * 512 + l * 8];   \
            _Pragma("unroll")                                                         \
            for (int nt = 0; nt < 8; ++nt)                                            \
                bfr[nt] = *(const bf16x8*)&Bs[(nt * 2 + kh) * 512 + l * 8];            \
            _Pragma("unroll")                                                         \
            for (int mt = 0; mt < 4; ++mt)                                            \
                _Pragma("unroll")                                                     \
                for (int nt = 0; nt < 8; ++nt)                                        \
                    acc[mt][nt] = __builtin_amdgcn_mfma_f32_16x16x32_bf16(            \
                        af[mt], bfr[nt], acc[mt][nt], 0, 0, 0);                       \
        }                                                                             \
    }

// ---------------- 128x128 GEMM: out = op(X @ W^T + b) (projections) ----------------
struct GemmDesc {
    const unsigned short* X;
    const unsigned short* W;
    const float* bias;
    unsigned short* out_bf;
    float* out_f32;
    int relu;
};
struct GemmArgs { GemmDesc d[5]; };

__launch_bounds__(256, 2)
__global__ void gemm128(GemmArgs args) {
    __shared__ __align__(16) unsigned short As[16 * 512];
    __shared__ __align__(16) unsigned short Bs[16 * 512];
    const GemmDesc d = args.d[blockIdx.y >> 2];
    const int n0 = (blockIdx.y & 3) * 128;
    const int m0 = blockIdx.x * 128;
    const int tid = threadIdx.x;
    const int w = tid >> 6, l = tid & 63, quad = l >> 4, ln = l & 15;
    const int wr = w >> 1, wc = w & 1;

    f32x4 acc[4][4];
    f32x4 zero4 = {0.f, 0.f, 0.f, 0.f};
#pragma unroll
    for (int i = 0; i < 4; ++i)
#pragma unroll
        for (int j = 0; j < 4; ++j) acc[i][j] = zero4;

    GEMM_KLOOP(d.X, F_DIM, d.W, F_DIM, 0, F_DIM)

#pragma unroll
    for (int mt = 0; mt < 4; ++mt)
#pragma unroll
        for (int nt = 0; nt < 4; ++nt)
#pragma unroll
            for (int r = 0; r < 4; ++r) {
                int row = m0 + wr * 64 + mt * 16 + quad * 4 + r;
                int col = n0 + wc * 64 + nt * 16 + ln;
                float vv = acc[mt][nt][r] + d.bias[col];
                if (d.relu) vv = fmaxf(vv, 0.f);
                if (d.out_bf)  d.out_bf[(size_t)row * F_DIM + col] = f2bf(vv);
                if (d.out_f32) d.out_f32[(size_t)row * F_DIM + col] = vv;
            }
}

// ---------------- gemm_exp (256x128): P = exp(scale*(qq @ kk^T) - M) + row-sum parts ----------------
__launch_bounds__(256, 2)
__global__ void gemm_exp(const unsigned short* __restrict__ X,   // qq [S][F]
                         const unsigned short* __restrict__ W,   // kk [S][F]
                         unsigned short* __restrict__ P,         // [S][S]
                         float* __restrict__ lpart) {            // [32][S]
    __shared__ __align__(16) unsigned short As[32 * 512];
    __shared__ __align__(16) unsigned short Bs[16 * 512];
    const float scale = 0.04415108f;  // 1/sqrt(513)
    const int nb = blockIdx.y;
    const int n0 = nb * 128;
    const int m0 = blockIdx.x * 256;
    const int tid = threadIdx.x;
    const int w = tid >> 6, l = tid & 63, quad = l >> 4, ln = l & 15;

    f32x4 acc[4][8];
    f32x4 zero4 = {0.f, 0.f, 0.f, 0.f};
#pragma unroll
    for (int i = 0; i < 4; ++i)
#pragma unroll
        for (int j = 0; j < 8; ++j) acc[i][j] = zero4;

    KLOOP256(X, F_DIM, W, F_DIM, 0, F_DIM)

#pragma unroll
    for (int mt = 0; mt < 4; ++mt)
#pragma unroll
        for (int r = 0; r < 4; ++r) {
            int row = m0 + w * 64 + mt * 16 + quad * 4 + r;
            float rs = 0.f;
#pragma unroll
            for (int nt = 0; nt < 8; ++nt) {
                int col = n0 + nt * 16 + ln;
                float p = __expf(acc[mt][nt][r] * scale - FIXED_M);
                P[(size_t)row * S_LEN + col] = f2bf(p);
                rs += p;
            }
            rs += __shfl_xor(rs, 1);
            rs += __shfl_xor(rs, 2);
            rs += __shfl_xor(rs, 4);
            rs += __shfl_xor(rs, 8);
            if (ln == 0) lpart[(size_t)nb * S_LEN + row] = rs;
        }
}

// ---------------- gemm_pv (256x128): O_p[split] = P[:, ks] @ vt[:, ks]^T (bf16) ----------------
// grid (16, 32): nb = y&3 (n0 over F), split = y>>2 (koff = split*512).
__launch_bounds__(256, 2)
__global__ void gemm_pv(const unsigned short* __restrict__ P,   // [S][S]
                        const unsigned short* __restrict__ vt,  // [F][S]
                        unsigned short* __restrict__ O_p) {     // [PSPLIT][S][F] bf16
    __shared__ __align__(16) unsigned short As[32 * 512];
    __shared__ __align__(16) unsigned short Bs[16 * 512];
    const int nb = blockIdx.y & 3;
    const int split = blockIdx.y >> 2;
    const int n0 = nb * 128;
    const int m0 = blockIdx.x * 256;
    const int koff = split * (S_LEN / PSPLIT);
    const int tid = threadIdx.x;
    const int w = tid >> 6, l = tid & 63, quad = l >> 4, ln = l & 15;

    f32x4 acc[4][8];
    f32x4 zero4 = {0.f, 0.f, 0.f, 0.f};
#pragma unroll
    for (int i = 0; i < 4; ++i)
#pragma unroll
        for (int j = 0; j < 8; ++j) acc[i][j] = zero4;

    KLOOP256(P, S_LEN, vt, S_LEN, koff, koff + S_LEN / PSPLIT)

    unsigned short* Op = O_p + (size_t)split * S_LEN * F_DIM;
#pragma unroll
    for (int mt = 0; mt < 4; ++mt)
#pragma unroll
        for (int nt = 0; nt < 8; ++nt)
#pragma unroll
            for (int r = 0; r < 4; ++r) {
                int row = m0 + w * 64 + mt * 16 + quad * 4 + r;
                int col = n0 + nt * 16 + ln;
                Op[(size_t)row * F_DIM + col] = f2bf(acc[mt][nt][r]);
            }
}

// ---------------- final projection, split-K=2: raw f32 partials ----------------
// grid (32, 8): nb = y&3, kseg = y>>2. K range [kseg*256, +256).
__launch_bounds__(256, 2)
__global__ void gemm_final(const unsigned short* __restrict__ X,   // res [S][F]
                           const unsigned short* __restrict__ W,   // Wo [F][F]
                           float* __restrict__ Fp) {               // [2][S][F]
    __shared__ __align__(16) unsigned short As[16 * 512];
    __shared__ __align__(16) unsigned short Bs[16 * 512];
    const int nb = blockIdx.y & 3;
    const int kseg = blockIdx.y >> 2;
    const int n0 = nb * 128;
    const int m0 = blockIdx.x * 128;
    const int tid = threadIdx.x;
    const int w = tid >> 6, l = tid & 63, quad = l >> 4, ln = l & 15;
    const int wr = w >> 1, wc = w & 1;

    f32x4 acc[4][4];
    f32x4 zero4 = {0.f, 0.f, 0.f, 0.f};
#pragma unroll
    for (int i = 0; i < 4; ++i)
#pragma unroll
        for (int j = 0; j < 4; ++j) acc[i][j] = zero4;

    GEMM_KLOOP(X, F_DIM, W, F_DIM, kseg * 256, kseg * 256 + 256)

    float* Op = Fp + (size_t)kseg * S_LEN * F_DIM;
#pragma unroll
    for (int mt = 0; mt < 4; ++mt)
#pragma unroll
        for (int nt = 0; nt < 4; ++nt)
#pragma unroll
            for (int r = 0; r < 4; ++r) {
                int row = m0 + wr * 64 + mt * 16 + quad * 4 + r;
                int col = n0 + wc * 64 + nt * 16 + ln;
                Op[(size_t)row * F_DIM + col] = acc[mt][nt][r];
            }
}

__global__ void reduce_final(const float* __restrict__ Fp,
                             const float* __restrict__ bias,
                             float* __restrict__ out) {
    int i = blockIdx.x * blockDim.x + threadIdx.x;  // float4 index over S*F/4
    int col4 = (i & (F_DIM / 4 - 1)) * 4;
    float4 a = ((const float4*)Fp)[i];
    float4 b = ((const float4*)(Fp + (size_t)S_LEN * F_DIM))[i];
    float4 bi = *(const float4*)(bias + col4);
    float4 o;
    o.x = fmaxf(a.x + b.x + bi.x, 0.f);
    o.y = fmaxf(a.y + b.y + bi.y, 0.f);
    o.z = fmaxf(a.z + b.z + bi.z, 0.f);
    o.w = fmaxf(a.w + b.w + bi.w, 0.f);
    ((float4*)out)[i] = o;
}

// ---------------- combine: denom + q_att dot + split-sum + elementwise fusion ----------------
__global__ void combine_kernel(const unsigned short* __restrict__ O_p,
                               const float* __restrict__ lpart,
                               const unsigned short* __restrict__ qq,
                               const unsigned short* __restrict__ qk,
                               const unsigned short* __restrict__ qv,
                               unsigned short* __restrict__ res_bf) {
    const float scale = 0.04415108f;
    int row = blockIdx.x;
    int t = threadIdx.x;  // 128 threads = 2 waves
    int wv = t >> 6, l = t & 63;
    __shared__ float wsum[2];

    ushort4 a = *(const ushort4*)(qq + (size_t)row * F_DIM + t * 4);
    ushort4 b = *(const ushort4*)(qk + (size_t)row * F_DIM + t * 4);
    float part = bf2f(a.x) * bf2f(b.x) + bf2f(a.y) * bf2f(b.y) +
                 bf2f(a.z) * bf2f(b.z) + bf2f(a.w) * bf2f(b.w);
#pragma unroll
    for (int off = 32; off >= 1; off >>= 1) part += __shfl_xor(part, off);
    if (l == 0) wsum[wv] = part;
    __syncthreads();
    float qa = wsum[0] + wsum[1];

    float denom = __expf(qa * scale - FIXED_M);  // extra column: denominator only
#pragma unroll
    for (int i = 0; i < 32; ++i) denom += lpart[(size_t)i * S_LEN + row];
    float inv = 1.f / denom;

    for (int f = t; f < F_DIM; f += 128) {
        float acc = 0.f;
#pragma unroll
        for (int i = 0; i < PSPLIT; ++i)
            acc += bf2f(O_p[((size_t)i * S_LEN + row) * F_DIM + f]);
        float r = bf2f(qv[(size_t)row * F_DIM + f]) * qa + acc * inv;
        res_bf[(size_t)row * F_DIM + f] = f2bf(r);
    }
}

extern "C" void kernel_launch(void* const* d_in, const int* in_sizes, int n_in,
                              void* d_out, int out_size, void* d_ws, size_t ws_size,
                              hipStream_t stream) {
    const float* q  = (const float*)d_in[0];
    const float* k  = (const float*)d_in[1];
    const float* v  = (const float*)d_in[2];
    const float* Wq = (const float*)d_in[3];
    const float* bq = (const float*)d_in[4];
    const float* Wk = (const float*)d_in[5];
    const float* bk = (const float*)d_in[6];
    const float* Wv = (const float*)d_in[7];
    const float* bv = (const float*)d_in[8];
    const float* Wo = (const float*)d_in[9];
    const float* bo = (const float*)d_in[10];
    float* out = (float*)d_out;

    char* p = (char*)d_ws;
    auto alloc = [&](size_t bytes) -> char* {
        char* r = p; p += (bytes + 255) & ~(size_t)255; return r;
    };
    const size_t SF = (size_t)S_LEN * F_DIM;
    unsigned short* q_bf  = (unsigned short*)alloc(SF * 2);
    unsigned short* k_bf  = (unsigned short*)alloc(SF * 2);
    unsigned short* v_bf  = (unsigned short*)alloc(SF * 2);
    unsigned short* qq_bf = (unsigned short*)alloc(SF * 2);
    unsigned short* kk_bf = (unsigned short*)alloc(SF * 2);
    unsigned short* vv_bf = (unsigned short*)alloc(SF * 2);
    unsigned short* vt_bf = (unsigned short*)alloc(SF * 2);
    unsigned short* qk_bf = (unsigned short*)alloc(SF * 2);
    unsigned short* qv_bf = (unsigned short*)alloc(SF * 2);
    unsigned short* res_bf = (unsigned short*)alloc(SF * 2);
    unsigned short* wq_bf = (unsigned short*)alloc((size_t)F_DIM * F_DIM * 2);
    unsigned short* wk_bf = (unsigned short*)alloc((size_t)F_DIM * F_DIM * 2);
    unsigned short* wv_bf = (unsigned short*)alloc((size_t)F_DIM * F_DIM * 2);
    unsigned short* wo_bf = (unsigned short*)alloc((size_t)F_DIM * F_DIM * 2);
    unsigned short* P_bf  = (unsigned short*)alloc((size_t)S_LEN * S_LEN * 2);  // 33.5 MB
    float* lpart = (float*)alloc((size_t)32 * S_LEN * 4);
    unsigned short* O_p = (unsigned short*)alloc((size_t)PSPLIT * SF * 2);      // 32 MB
    float* Fp = (float*)alloc((size_t)2 * SF * 4);                              // 16 MB

    CastArgs ca;
    ca.src[0] = q;  ca.dst[0] = q_bf;  ca.n4[0] = (int)(SF / 4);
    ca.src[1] = k;  ca.dst[1] = k_bf;  ca.n4[1] = (int)(SF / 4);
    ca.src[2] = v;  ca.dst[2] = v_bf;  ca.n4[2] = (int)(SF / 4);
    ca.src[3] = Wq; ca.dst[3] = wq_bf; ca.n4[3] = F_DIM * F_DIM / 4;
    ca.src[4] = Wk; ca.dst[4] = wk_bf; ca.n4[4] = F_DIM * F_DIM / 4;
    ca.src[5] = Wv; ca.dst[5] = wv_bf; ca.n4[5] = F_DIM * F_DIM / 4;
    ca.src[6] = Wo; ca.dst[6] = wo_bf; ca.n4[6] = F_DIM * F_DIM / 4;
    cast_all<<<dim3((unsigned)(SF / 4 / 256), 7), 256, 0, stream>>>(ca);

    GemmArgs ga;
    ga.d[0] = { q_bf, wq_bf, bq, qq_bf, nullptr, 1 };
    ga.d[1] = { k_bf, wk_bf, bk, kk_bf, nullptr, 1 };
    ga.d[2] = { v_bf, wv_bf, bv, vv_bf, nullptr, 1 };
    ga.d[3] = { q_bf, wk_bf, bk, qk_bf, nullptr, 0 };
    ga.d[4] = { q_bf, wv_bf, bv, qv_bf, nullptr, 0 };
    gemm128<<<dim3(S_LEN / 128, 20), 256, 0, stream>>>(ga);

    transpose_bf16<<<dim3(S_LEN / 64, F_DIM / 64), 256, 0, stream>>>(vv_bf, vt_bf);

    gemm_exp<<<dim3(S_LEN / 256, S_LEN / 128), 256, 0, stream>>>(qq_bf, kk_bf, P_bf, lpart);

    gemm_pv<<<dim3(S_LEN / 256, 4 * PSPLIT), 256, 0, stream>>>(P_bf, vt_bf, O_p);

    combine_kernel<<<S_LEN, 128, 0, stream>>>(O_p, lpart, qq_bf, qk_bf, qv_bf, res_bf);

    gemm_final<<<dim3(S_LEN / 128, 8), 256, 0, stream>>>(res_bf, wo_bf, Fp);
    reduce_final<<<(unsigned)(SF / 4 / 256), 256, 0, stream>>>(Fp, bo, out);
}